// Round 3
// baseline (503.421 us; speedup 1.0000x reference)
//
#include <hip/hip_runtime.h>
#include <math.h>

#define NEG_SLOPE 0.2f

typedef short bf16x8 __attribute__((ext_vector_type(8)));
typedef float f32x4 __attribute__((ext_vector_type(4)));

__device__ __forceinline__ unsigned short f32_to_bf16_rne(float x) {
  unsigned int u = __float_as_uint(x);
  unsigned int r = u + 0x7FFFu + ((u >> 16) & 1u);
  return (unsigned short)(r >> 16);
}
__device__ __forceinline__ float bf16_bits_to_f32(unsigned short h) {
  return __uint_as_float((unsigned int)h << 16);
}

// ---------------- CSR build ----------------
__global__ void hist_kernel(const int* __restrict__ dst, int* __restrict__ cnt, int E) {
  int i = blockIdx.x * blockDim.x + threadIdx.x;
  if (i < E) atomicAdd(&cnt[dst[i]], 1);
}

__global__ __launch_bounds__(1024) void scan_block_kernel(const int* __restrict__ cnt,
                                                          int* __restrict__ row_start,
                                                          int* __restrict__ blk, int n) {
  __shared__ int buf[1024];
  int i = blockIdx.x * 1024 + threadIdx.x;
  int v = (i < n) ? cnt[i] : 0;
  buf[threadIdx.x] = v;
  __syncthreads();
  for (int off = 1; off < 1024; off <<= 1) {
    int t = (threadIdx.x >= (unsigned)off) ? buf[threadIdx.x - off] : 0;
    __syncthreads();
    buf[threadIdx.x] += t;
    __syncthreads();
  }
  if (i < n) row_start[i] = buf[threadIdx.x] - v;  // exclusive within block
  if (threadIdx.x == 1023) blk[blockIdx.x] = buf[1023];
}

__global__ __launch_bounds__(1024) void scan_tops_kernel(int* __restrict__ blk, int nb) {
  __shared__ int buf[1024];
  int v = (threadIdx.x < (unsigned)nb) ? blk[threadIdx.x] : 0;
  buf[threadIdx.x] = v;
  __syncthreads();
  for (int off = 1; off < 1024; off <<= 1) {
    int t = (threadIdx.x >= (unsigned)off) ? buf[threadIdx.x - off] : 0;
    __syncthreads();
    buf[threadIdx.x] += t;
    __syncthreads();
  }
  if (threadIdx.x < (unsigned)nb) blk[threadIdx.x] = buf[threadIdx.x] - v;  // exclusive
}

__global__ void scan_fixup_kernel(int* __restrict__ row_start, int* __restrict__ cursor,
                                  const int* __restrict__ blk, int n, int total) {
  int i = blockIdx.x * blockDim.x + threadIdx.x;
  if (i < n) {
    int r = row_start[i] + blk[i >> 10];
    row_start[i] = r;
    cursor[i] = r;
  }
  if (i == 0) row_start[n] = total;
}

__global__ void scatter_kernel(const int* __restrict__ dst, const int* __restrict__ src,
                               int* __restrict__ cursor, int* __restrict__ src_sorted, int E) {
  int i = blockIdx.x * blockDim.x + threadIdx.x;
  if (i < E) {
    int p = atomicAdd(&cursor[dst[i]], 1);
    src_sorted[p] = src[i];
  }
}

// ---------------- weight fragment pre-pack (hi/lo bf16, MFMA B-operand order) ----------------
// B-frag layout for mfma_f32_16x16x32_bf16: lane l holds col = l&15, k = (l>>4)*8 + j.
// Buffer layout: [mat(4)][ks(4)][nb(8)][lane(64)][j(8)]  (16B per lane -> coalesced frag loads)
__global__ void wfrag_kernel(const float* __restrict__ W0, const float* __restrict__ W1,
                             const float* __restrict__ W2, const float* __restrict__ W3,
                             unsigned short* __restrict__ hi, unsigned short* __restrict__ lo) {
  int t = blockIdx.x * 256 + threadIdx.x;  // 4 * 2048
  if (t >= 4 * 2048) return;
  int mat = t >> 11;
  int u = t & 2047;
  int l = u & 63, nb = (u >> 6) & 7, ks = u >> 9;
  const float* W = mat == 0 ? W0 : mat == 1 ? W1 : mat == 2 ? W2 : W3;
  int col = nb * 16 + (l & 15);
  int k0 = ks * 32 + ((l >> 4) << 3);
  unsigned short hv[8], lv[8];
#pragma unroll
  for (int j = 0; j < 8; j++) {
    float x = W[(size_t)(k0 + j) * 128 + col];
    unsigned short h = f32_to_bf16_rne(x);
    hv[j] = h;
    lv[j] = f32_to_bf16_rne(x - bf16_bits_to_f32(h));
  }
  size_t o = (size_t)t * 8;
#pragma unroll
  for (int j = 0; j < 8; j++) { hi[o + j] = hv[j]; lo[o + j] = lv[j]; }
}

// ---------------- dual GEMM via 3xBF16 MFMA ----------------
// P[M,128] = A@Ws + bs ; Q[M,128] = A@Wd + bd.  A fp32, split to hi/lo bf16 in-register.
// Block: 256 thr = 4 waves; wave w owns rows blockIdx.x*64 + w*16 .. +15; full N=128.
__global__ __launch_bounds__(256) void gemm_mfma_dual(
    const float* __restrict__ A,
    const unsigned short* __restrict__ FSh, const unsigned short* __restrict__ FSl,
    const unsigned short* __restrict__ FDh, const unsigned short* __restrict__ FDl,
    const float* __restrict__ bs_, const float* __restrict__ bd_,
    float* __restrict__ P, float* __restrict__ Q, int M) {
  const int tid = (int)threadIdx.x;
  const int w = tid >> 6;
  const int l = tid & 63;
  const int r0 = blockIdx.x * 64 + w * 16;
  const int arow = r0 + (l & 15);          // A-frag: row = lane&15
  const int koff = (l >> 4) << 3;          // A/B-frag: k = (lane>>4)*8 + j
  f32x4 accP[8] = {{0.f, 0.f, 0.f, 0.f}};
  f32x4 accQ[8] = {{0.f, 0.f, 0.f, 0.f}};
#pragma unroll
  for (int nb = 1; nb < 8; nb++) { accP[nb] = accP[0]; accQ[nb] = accQ[0]; }
  const bf16x8* fsh = (const bf16x8*)FSh;
  const bf16x8* fsl = (const bf16x8*)FSl;
  const bf16x8* fdh = (const bf16x8*)FDh;
  const bf16x8* fdl = (const bf16x8*)FDl;
#pragma unroll
  for (int ks = 0; ks < 4; ks++) {
    bf16x8 ahi, alo;
    if (arow < M) {
      const float* ap = A + (size_t)arow * 128 + ks * 32 + koff;
      float4 v0 = *(const float4*)ap;
      float4 v1 = *(const float4*)(ap + 4);
      float va[8] = {v0.x, v0.y, v0.z, v0.w, v1.x, v1.y, v1.z, v1.w};
#pragma unroll
      for (int j = 0; j < 8; j++) {
        unsigned short h = f32_to_bf16_rne(va[j]);
        ahi[j] = (short)h;
        alo[j] = (short)f32_to_bf16_rne(va[j] - bf16_bits_to_f32(h));
      }
    } else {
#pragma unroll
      for (int j = 0; j < 8; j++) { ahi[j] = 0; alo[j] = 0; }
    }
#pragma unroll
    for (int nb = 0; nb < 8; nb++) {
      int fi = (ks * 8 + nb) * 64 + l;
      bf16x8 bsh = fsh[fi];
      bf16x8 bsl = fsl[fi];
      bf16x8 bdh = fdh[fi];
      bf16x8 bdl = fdl[fi];
      accP[nb] = __builtin_amdgcn_mfma_f32_16x16x32_bf16(ahi, bsh, accP[nb], 0, 0, 0);
      accP[nb] = __builtin_amdgcn_mfma_f32_16x16x32_bf16(alo, bsh, accP[nb], 0, 0, 0);
      accP[nb] = __builtin_amdgcn_mfma_f32_16x16x32_bf16(ahi, bsl, accP[nb], 0, 0, 0);
      accQ[nb] = __builtin_amdgcn_mfma_f32_16x16x32_bf16(ahi, bdh, accQ[nb], 0, 0, 0);
      accQ[nb] = __builtin_amdgcn_mfma_f32_16x16x32_bf16(alo, bdh, accQ[nb], 0, 0, 0);
      accQ[nb] = __builtin_amdgcn_mfma_f32_16x16x32_bf16(ahi, bdl, accQ[nb], 0, 0, 0);
    }
  }
  // D-frag: col = lane&15, row = (lane>>4)*4 + reg   [m89-verified mapping]
  const int rbase = r0 + ((l >> 4) << 2);
  const int cl = l & 15;
#pragma unroll
  for (int nb = 0; nb < 8; nb++) {
    int col = nb * 16 + cl;
    float bP = bs_[col], bQ = bd_[col];
#pragma unroll
    for (int r = 0; r < 4; r++) {
      int grow = rbase + r;
      if (grow < M) {
        P[(size_t)grow * 128 + col] = accP[nb][r] + bP;
        Q[(size_t)grow * 128 + col] = accQ[nb][r] + bQ;
      }
    }
  }
}

// ---------------- GATv2 aggregation: one wave per dst node, online softmax ----------------
__global__ __launch_bounds__(256) void gat_agg_kernel(
    const float* __restrict__ P,      // fs [N,128]
    const float* __restrict__ Q,      // fd [N,128]
    const float* __restrict__ attn,   // [128] = [H=4][D=32]
    const int* __restrict__ row_start,
    const int* __restrict__ src_sorted,
    float* __restrict__ out, int N, int do_relu) {
  int wave = (int)((blockIdx.x * blockDim.x + threadIdx.x) >> 6);
  int lane = (int)(threadIdx.x & 63);
  if (wave >= N) return;
  const int n = wave;
  const int off = lane * 2;
  float2 fd = *(const float2*)&Q[(size_t)n * 128 + off];
  float2 av = *(const float2*)&attn[off];
  const int s0 = row_start[n], s1 = row_start[n + 1];

  float m = -INFINITY, denom = 0.f, acc0 = 0.f, acc1 = 0.f;
  int i = s0;
  int sN = 0;
  float2 fsN = make_float2(0.f, 0.f);
  if (i < s1) {
    sN = src_sorted[i];
    fsN = *(const float2*)&P[(size_t)sN * 128 + off];
  }
  while (i < s1) {
    float2 fs = fsN;
    int inext = i + 1;
    if (inext < s1) {                      // prefetch next edge's feature row
      sN = src_sorted[inext];
      fsN = *(const float2*)&P[(size_t)sN * 128 + off];
    }
    float x0 = fs.x + fd.x, x1 = fs.y + fd.y;
    x0 = x0 > 0.f ? x0 : NEG_SLOPE * x0;
    x1 = x1 > 0.f ? x1 : NEG_SLOPE * x1;
    float t = x0 * av.x + x1 * av.y;       // per-head dot over the head's 16 lanes
    t += __shfl_xor(t, 1, 16);
    t += __shfl_xor(t, 2, 16);
    t += __shfl_xor(t, 4, 16);
    t += __shfl_xor(t, 8, 16);
    float mn = fmaxf(m, t);                // branchless online softmax
    float sc = __expf(m - mn);
    float ex = __expf(t - mn);
    denom = denom * sc + ex;
    acc0 = acc0 * sc + ex * fs.x;
    acc1 = acc1 * sc + ex * fs.y;
    m = mn;
    i = inext;
  }

  float2 o;
  if (s1 > s0) { o.x = acc0 / denom; o.y = acc1 / denom; }
  else         { o.x = 0.f; o.y = 0.f; }
  if (do_relu) { o.x = fmaxf(o.x, 0.f); o.y = fmaxf(o.y, 0.f); }
  *(float2*)&out[(size_t)n * 128 + off] = o;
}

// ---------------- link-prediction scores: one wave per query ----------------
__global__ __launch_bounds__(256) void edge_score_kernel(
    const float* __restrict__ H, const int* __restrict__ qs, const int* __restrict__ qd,
    float* __restrict__ out, int NQ) {
  int wave = (int)((blockIdx.x * blockDim.x + threadIdx.x) >> 6);
  int lane = (int)(threadIdx.x & 63);
  if (wave >= NQ) return;
  int a = qs[wave], b = qd[wave];
  float2 x = *(const float2*)&H[(size_t)a * 128 + lane * 2];
  float2 y = *(const float2*)&H[(size_t)b * 128 + lane * 2];
  float t = x.x * y.x + x.y * y.y;
#pragma unroll
  for (int mask = 1; mask < 64; mask <<= 1) t += __shfl_xor(t, mask, 64);
  if (lane == 0) out[wave] = 1.f / (1.f + __expf(-t));
}

// ---------------- launch ----------------
extern "C" void kernel_launch(void* const* d_in, const int* in_sizes, int n_in,
                              void* d_out, int out_size, void* d_ws, size_t ws_size,
                              hipStream_t stream) {
  const float* feat  = (const float*)d_in[0];
  const int*   esrc  = (const int*)d_in[1];
  const int*   edst  = (const int*)d_in[2];
  const int*   qsrc  = (const int*)d_in[3];
  const int*   qdst  = (const int*)d_in[4];
  const float* W1s   = (const float*)d_in[5];
  const float* b1s   = (const float*)d_in[6];
  const float* W1d   = (const float*)d_in[7];
  const float* b1d   = (const float*)d_in[8];
  const float* attn1 = (const float*)d_in[9];
  const float* W2s   = (const float*)d_in[10];
  const float* b2s   = (const float*)d_in[11];
  const float* W2d   = (const float*)d_in[12];
  const float* b2d   = (const float*)d_in[13];
  const float* attn2 = (const float*)d_in[14];
  float* out = (float*)d_out;

  const int N  = in_sizes[0] / 128;
  const int E  = in_sizes[1];
  const int NQ = in_sizes[3];

  char* p = (char*)d_ws;
  auto alloc = [&](size_t bytes) -> char* {
    char* r = p;
    p += (bytes + 255) & ~(size_t)255;
    return r;
  };
  float* P          = (float*)alloc((size_t)N * 128 * 4);
  float* Q          = (float*)alloc((size_t)N * 128 * 4);
  float* H          = (float*)alloc((size_t)N * 128 * 4);
  int*   cnt        = (int*)alloc((size_t)N * 4);
  int*   row_start  = (int*)alloc((size_t)(N + 1) * 4);
  int*   cursor     = (int*)alloc((size_t)N * 4);
  int*   src_sorted = (int*)alloc((size_t)E * 4);
  int*   blk        = (int*)alloc(1024 * 4);
  unsigned short* FBhi = (unsigned short*)alloc(4 * 2048 * 8 * 2);  // 128KB
  unsigned short* FBlo = (unsigned short*)alloc(4 * 2048 * 8 * 2);

  // weight fragment pre-pack (independent of graph build)
  wfrag_kernel<<<32, 256, 0, stream>>>(W1s, W1d, W2s, W2d, FBhi, FBlo);

  // CSR build (edges grouped by dst; order within a node is arbitrary — sums only)
  const int nb = (N + 1023) / 1024;
  hipMemsetAsync(cnt, 0, (size_t)N * 4, stream);
  hist_kernel<<<(E + 255) / 256, 256, 0, stream>>>(edst, cnt, E);
  scan_block_kernel<<<nb, 1024, 0, stream>>>(cnt, row_start, blk, N);
  scan_tops_kernel<<<1, 1024, 0, stream>>>(blk, nb);
  scan_fixup_kernel<<<(N + 255) / 256, 256, 0, stream>>>(row_start, cursor, blk, N, E);
  scatter_kernel<<<(E + 255) / 256, 256, 0, stream>>>(edst, esrc, cursor, src_sorted, E);

  const int gblocks = (N + 63) / 64;
  const int per_mat = 2048 * 8;  // ushorts per matrix in FB buffers

  // layer 1
  gemm_mfma_dual<<<gblocks, 256, 0, stream>>>(
      feat, FBhi + 0 * per_mat, FBlo + 0 * per_mat, FBhi + 1 * per_mat, FBlo + 1 * per_mat,
      b1s, b1d, P, Q, N);
  gat_agg_kernel<<<(N + 3) / 4, 256, 0, stream>>>(P, Q, attn1, row_start, src_sorted, H, N, 1);

  // layer 2
  gemm_mfma_dual<<<gblocks, 256, 0, stream>>>(
      H, FBhi + 2 * per_mat, FBlo + 2 * per_mat, FBhi + 3 * per_mat, FBlo + 3 * per_mat,
      b2s, b2d, P, Q, N);
  gat_agg_kernel<<<(N + 3) / 4, 256, 0, stream>>>(P, Q, attn2, row_start, src_sorted, H, N, 0);

  // scores
  edge_score_kernel<<<(NQ + 3) / 4, 256, 0, stream>>>(H, qsrc, qdst, out, NQ);
}